// Round 6
// baseline (1295.414 us; speedup 1.0000x reference)
//
#include <hip/hip_runtime.h>

typedef unsigned short u16;
typedef __bf16 bf16t;
typedef bf16t v8bf __attribute__((ext_vector_type(8)));
typedef float v4f __attribute__((ext_vector_type(4)));

#define Bb 64
#define Tt 20
#define Tm 19
#define Pp 36
#define Vv 32000
#define Ee 300
#define Ep 320
#define Hh 512
#define Dd 512
#define Gg 2048
#define Mtot (Bb * Tm)   // 1216
#define Mpad 1280

__device__ __forceinline__ u16 f2b(float f) {
    unsigned u = __builtin_bit_cast(unsigned, f);
    unsigned r = u + 0x7fffu + ((u >> 16) & 1u);
    return (u16)(r >> 16);
}
__device__ __forceinline__ float b2f(u16 x) {
    return __builtin_bit_cast(float, (unsigned)x << 16);
}
__device__ __forceinline__ v8bf ld8(const u16* p) {
    return *reinterpret_cast<const v8bf*>(p);
}

__global__ void k_sentinel_r6(float* __restrict__ out, float val)
{
    int i = blockIdx.x * 256 + threadIdx.x;
    if (i < 8192) out[i] = val;
}

// ---------------- device 64x64 bt-GEMM tile ----------------
// EPI 0: Cf = acc + addN[n];  EPI 1: Cb = bf16(acc)
template<int EPI>
__device__ __forceinline__ void gemm_tile64(
    const u16* __restrict__ A, const u16* __restrict__ B,
    int lda, int ldb, int K,
    float* __restrict__ Cf, u16* __restrict__ Cb, int ldc,
    const float* __restrict__ addN, int bn, int bm)
{
    const int tid = threadIdx.x;
    const int w = tid >> 6, l = tid & 63;
    const int lr = l & 15, lk = (l >> 4) << 3;
    const int m0 = bm * 64;
    const int n0 = bn * 64 + w * 16;
    const u16* Ap = A + (size_t)(m0 + lr) * lda + lk;
    const u16* Bp = B + (size_t)(n0 + lr) * ldb + lk;
    v4f acc0 = {0.f,0.f,0.f,0.f}, acc1 = {0.f,0.f,0.f,0.f},
        acc2 = {0.f,0.f,0.f,0.f}, acc3 = {0.f,0.f,0.f,0.f};
    for (int k = 0; k < K; k += 32) {
        v8bf bf = ld8(Bp + k);
        v8bf a0 = ld8(Ap + k);
        v8bf a1 = ld8(Ap + (size_t)16 * lda + k);
        v8bf a2 = ld8(Ap + (size_t)32 * lda + k);
        v8bf a3 = ld8(Ap + (size_t)48 * lda + k);
        acc0 = __builtin_amdgcn_mfma_f32_16x16x32_bf16(a0, bf, acc0, 0, 0, 0);
        acc1 = __builtin_amdgcn_mfma_f32_16x16x32_bf16(a1, bf, acc1, 0, 0, 0);
        acc2 = __builtin_amdgcn_mfma_f32_16x16x32_bf16(a2, bf, acc2, 0, 0, 0);
        acc3 = __builtin_amdgcn_mfma_f32_16x16x32_bf16(a3, bf, acc3, 0, 0, 0);
    }
    v4f accs[4] = {acc0, acc1, acc2, acc3};
    const int crow0 = (l >> 4) * 4;
    const int n = n0 + lr;
    #pragma unroll
    for (int i = 0; i < 4; ++i) {
        #pragma unroll
        for (int r = 0; r < 4; ++r) {
            int m = m0 + i * 16 + crow0 + r;
            float v = accs[i][r];
            if (EPI == 0) Cf[(size_t)m * ldc + n] = v + addN[n];
            else          Cb[(size_t)m * ldc + n] = f2b(v);
        }
    }
}

// ---------------- k_pre: all precompute, block-range dispatched ----------------
// [0,8000): embcast  [8000,8640): weight casts  [8640,8960): colsum partials
// [8960,9024): gather  [9024,9088): props  [9088]: sort
#define GPRE 9089
__global__ __launch_bounds__(256) void k_pre_r6(
    const float* __restrict__ h0, const float* __restrict__ props,
    const int* __restrict__ captions, const int* __restrict__ cap_len,
    const float* __restrict__ emb_W, const float* __restrict__ W_ih,
    const float* __restrict__ W_hh, const float* __restrict__ wh_W,
    const float* __restrict__ wr_W, const float* __restrict__ rh_W,
    const float* __restrict__ b_ih, const float* __restrict__ b_hh,
    const float* __restrict__ w_W, const float* __restrict__ w_b,
    const float* __restrict__ wr_b,
    u16* __restrict__ embp, float* __restrict__ w_lin, float* __restrict__ partialc,
    u16* __restrict__ Wc, u16* __restrict__ WihE, u16* __restrict__ BtWh,
    u16* __restrict__ BtWr, u16* __restrict__ rh_bf, float* __restrict__ bias_cat,
    float* __restrict__ h_state, u16* __restrict__ xin2, int* __restrict__ caps_s,
    float* __restrict__ out_caps,
    u16* __restrict__ props_bf, u16* __restrict__ S_bf, float* __restrict__ swrb,
    int* __restrict__ dec_i, float* __restrict__ out_dec, float* __restrict__ out_sort,
    int* __restrict__ sync_cnt)
{
    const int blk = blockIdx.x, tid = threadIdx.x;
    const int w = tid >> 6, l = tid & 63;
    __shared__ int len_s[64];
    __shared__ int src_s;
    __shared__ float red[256];

    if (blk < 8000) {
        // embcast: 4 vocab rows per block; bf16 cast + w_lin dot (no atomics)
        int v = blk * 4 + w;
        float acc = 0.f;
        for (int e = l; e < Ep; e += 64) {
            float x = (e < Ee) ? emb_W[(size_t)v * Ee + e] : 0.f;
            embp[(size_t)v * Ep + e] = f2b(x);
            if (e < Ee) acc += x * w_W[e];
        }
        for (int off = 32; off > 0; off >>= 1) acc += __shfl_down(acc, off);
        if (l == 0) w_lin[v] = acc + w_b[0];
    } else if (blk < 8640) {
        int cb = blk - 8000;
        {
            int e = cb;
            const float* W; u16* O;
            if (e < Ep) { W = wh_W; O = BtWh; }
            else { W = wr_W; O = BtWr; e -= Ep; }
            for (int h = tid; h < Hh; h += 256) {
                float v = (e < Ee) ? W[(size_t)h * Ee + e] : 0.f;
                O[(size_t)e * Hh + h] = f2b(v);
            }
        }
        if (cb < 512) {
            int j = cb * 4 + w;
            for (int k = l; k < 1024; k += 64) {
                float v = (k < 512) ? W_ih[(size_t)j * 812 + 300 + k]
                                    : W_hh[(size_t)j * 512 + (k - 512)];
                Wc[(size_t)j * 1024 + k] = f2b(v);
            }
            for (int e = l; e < Ep; e += 64) {
                float v = (e < Ee) ? W_ih[(size_t)j * 812 + e] : 0.f;
                WihE[(size_t)j * Ep + e] = f2b(v);
            }
        }
        if (cb < 128) {
            int h = cb * 4 + w;
            for (int d = l; d < Dd; d += 64)
                rh_bf[(size_t)h * Dd + d] = f2b(rh_W[(size_t)h * Dd + d]);
        }
        if (cb < 8) {
            int j = cb * 256 + tid;
            bias_cat[j] = b_ih[j] + b_hh[j];
        }
    } else if (blk < 8960) {
        // colsum partials: 100 vocab rows per block
        int pidx = blk - 8640;
        int r0 = pidx * 100;
        for (int e = tid; e < Ep; e += 256) {
            float s = 0.f;
            if (e < Ee)
                for (int r = 0; r < 100; ++r) s += emb_W[(size_t)(r0 + r) * Ee + e];
            partialc[(size_t)pidx * Ep + e] = s;
        }
    } else if (blk < 9088) {
        // gather (b<64) / props (b>=64): recompute sort rank locally
        int role = (blk < 9024) ? 0 : 1;
        int b = (role == 0) ? (blk - 8960) : (blk - 9024);
        if (tid < 64) len_s[tid] = cap_len[tid];
        __syncthreads();
        if (tid < 64) {
            int li = len_s[tid];
            int rank = 0;
            for (int j = 0; j < 64; ++j) {
                int lj = len_s[j];
                rank += (lj > li) || (lj == li && j < tid);
            }
            if (rank == b) src_s = tid;
        }
        __syncthreads();
        int src = src_s;
        if (role == 0) {
            for (int d = tid; d < Hh; d += 256) {
                float v = h0[(size_t)src * Hh + d];
                h_state[b * Hh + d] = v;
                xin2[(size_t)b * 1024 + d] = 0;
                xin2[(size_t)b * 1024 + Hh + d] = f2b(v);
            }
            if (tid < Tt) {
                int cp = captions[src * Tt + tid];
                caps_s[b * Tt + tid] = cp;
                if (tid >= 1) out_caps[b * Tm + (tid - 1)] = (float)cp;
            }
        } else {
            float s0 = 0.f, s1 = 0.f;
            for (int pp = 0; pp < Pp; ++pp) {
                size_t si = ((size_t)src * Pp + pp) * Dd;
                size_t di = ((size_t)b * Pp + pp) * Dd;
                float v0 = props[si + tid];
                float v1 = props[si + tid + 256];
                props_bf[di + tid] = f2b(v0);
                props_bf[di + tid + 256] = f2b(v1);
                s0 += v0; s1 += v1;
            }
            S_bf[b * Dd + tid] = f2b(s0);
            S_bf[b * Dd + tid + 256] = f2b(s1);
            red[tid] = s0 * wr_b[tid] + s1 * wr_b[tid + 256];
            __syncthreads();
            for (int s = 128; s > 0; s >>= 1) {
                if (tid < s) red[tid] += red[tid + s];
                __syncthreads();
            }
            if (tid == 0) swrb[b] = red[0];
        }
    } else {
        // sort outputs + zero sync counter
        if (tid < 64) len_s[tid] = cap_len[tid];
        __syncthreads();
        if (tid < 64) {
            int li = len_s[tid];
            int rank = 0;
            for (int j = 0; j < 64; ++j) {
                int lj = len_s[j];
                rank += (lj > li) || (lj == li && j < tid);
            }
            dec_i[rank] = li - 1;
            out_dec[rank] = (float)(li - 1);
            out_sort[rank] = (float)tid;
        }
        if (tid == 0) sync_cnt[0] = 0;
    }
}

// ---------------- k_gemms: gates_e (gather) + RH + Sw + sums ----------------
// [0,608): gates_e  [608,896): RH  [896,901): Sw  [901,906): sums
__global__ __launch_bounds__(256) void k_gemms_r6(
    const u16* __restrict__ embp, const int* __restrict__ caps_s,
    const u16* __restrict__ WihE, const float* __restrict__ bias_cat,
    u16* __restrict__ gates_e,
    const u16* __restrict__ props_bf, const u16* __restrict__ rh_bf,
    const float* __restrict__ rh_b, float* __restrict__ RH,
    const u16* __restrict__ S_bf, const u16* __restrict__ BtWr, u16* __restrict__ Sw,
    const float* __restrict__ partialc,
    const float* __restrict__ wh_W, const float* __restrict__ wh_b,
    const float* __restrict__ wr_W, const float* __restrict__ wr_b,
    const float* __restrict__ w_W, const float* __restrict__ w_b,
    float* __restrict__ sum_WH, float* __restrict__ sum_WRp, float* __restrict__ sum_wl)
{
    const int blk = blockIdx.x;
    if (blk < 608) {
        // gates_e = bf16(embp[caps] @ WihE^T + bias_cat), rows m = t*64 + b
        const int bn = blk & 31, bm = blk >> 5;   // 32 n-tiles x 19 m-tiles
        const int tid = threadIdx.x;
        const int w = tid >> 6, l = tid & 63;
        const int lr = l & 15, lk = (l >> 4) << 3;
        const int t = bm;
        const int n0 = bn * 64 + w * 16;
        int cap[4];
        #pragma unroll
        for (int i = 0; i < 4; ++i) {
            int c = caps_s[(lr + 16 * i) * Tt + t];
            cap[i] = c < 0 ? 0 : (c > Vv - 1 ? Vv - 1 : c);
        }
        const u16* A0 = embp + (size_t)cap[0] * Ep + lk;
        const u16* A1 = embp + (size_t)cap[1] * Ep + lk;
        const u16* A2 = embp + (size_t)cap[2] * Ep + lk;
        const u16* A3 = embp + (size_t)cap[3] * Ep + lk;
        const u16* Bp = WihE + (size_t)(n0 + lr) * Ep + lk;
        v4f acc0 = {0.f,0.f,0.f,0.f}, acc1 = {0.f,0.f,0.f,0.f},
            acc2 = {0.f,0.f,0.f,0.f}, acc3 = {0.f,0.f,0.f,0.f};
        for (int k = 0; k < Ep; k += 32) {
            v8bf bf = ld8(Bp + k);
            acc0 = __builtin_amdgcn_mfma_f32_16x16x32_bf16(ld8(A0 + k), bf, acc0, 0, 0, 0);
            acc1 = __builtin_amdgcn_mfma_f32_16x16x32_bf16(ld8(A1 + k), bf, acc1, 0, 0, 0);
            acc2 = __builtin_amdgcn_mfma_f32_16x16x32_bf16(ld8(A2 + k), bf, acc2, 0, 0, 0);
            acc3 = __builtin_amdgcn_mfma_f32_16x16x32_bf16(ld8(A3 + k), bf, acc3, 0, 0, 0);
        }
        v4f accs[4] = {acc0, acc1, acc2, acc3};
        const int crow0 = (l >> 4) * 4;
        const int n = n0 + lr;
        #pragma unroll
        for (int i = 0; i < 4; ++i) {
            #pragma unroll
            for (int r = 0; r < 4; ++r) {
                int b = i * 16 + crow0 + r;
                gates_e[((size_t)t * 64 + b) * Gg + n] = f2b(accs[i][r] + bias_cat[n]);
            }
        }
    } else if (blk < 896) {
        int idx = blk - 608;
        gemm_tile64<0>(props_bf, rh_bf, Dd, Dd, Dd, RH, nullptr, Hh, rh_b,
                       idx & 7, idx >> 3);
    } else if (blk < 901) {
        gemm_tile64<1>(S_bf, BtWr, Dd, Hh, Dd, nullptr, Sw, Ep, nullptr,
                       blk - 896, 0);
    } else {
        const int sidx = blk - 901;  // 0..4
        __shared__ float col[Ep];
        for (int e = threadIdx.x; e < Ep; e += 256) {
            float s = 0.f;
            for (int p2 = 0; p2 < 320; ++p2) s += partialc[(size_t)p2 * Ep + e];
            col[e] = s;
        }
        __syncthreads();
        if (sidx < 4) {
            int j = sidx * 256 + threadIdx.x;
            const float* W; const float* bias; float* o; int jj;
            if (j < Hh) { W = wh_W; bias = wh_b; o = sum_WH; jj = j; }
            else { W = wr_W; bias = wr_b; o = sum_WRp; jj = j - Hh; }
            float s = 0.f;
            for (int e = 0; e < Ee; ++e) s += col[e] * W[(size_t)jj * Ee + e];
            o[jj] = s + 32000.f * bias[jj];
        } else {
            __shared__ float red2[256];
            float s = 0.f;
            for (int e = threadIdx.x; e < Ee; e += 256) s += col[e] * w_W[e];
            red2[threadIdx.x] = s;
            __syncthreads();
            for (int st = 128; st > 0; st >>= 1) {
                if (threadIdx.x < st) red2[threadIdx.x] += red2[threadIdx.x + st];
                __syncthreads();
            }
            if (threadIdx.x == 0) sum_wl[0] = red2[0] + 32000.f * w_b[0];
        }
    }
}

// ---------------- persistent recurrence kernel ----------------
__device__ __forceinline__ void gbar(int* cnt, int target)
{
    __syncthreads();
    if (threadIdx.x == 0) {
        __threadfence();
        __hip_atomic_fetch_add(cnt, 1, __ATOMIC_ACQ_REL, __HIP_MEMORY_SCOPE_AGENT);
        long spins = 0;
        while (__hip_atomic_load(cnt, __ATOMIC_ACQUIRE, __HIP_MEMORY_SCOPE_AGENT) < target) {
            __builtin_amdgcn_s_sleep(2);
            if (++spins > (1L << 24)) break;   // failsafe: never hang the bench
        }
        __threadfence();
    }
    __syncthreads();
}

__global__ __launch_bounds__(256) void k_loop_r6(
    const u16* __restrict__ Wc, const u16* __restrict__ gates_e,
    const float* __restrict__ sum_WH, const float* __restrict__ sum_wl,
    const float* __restrict__ sum_WRp,
    const float* __restrict__ RH, const u16* __restrict__ props_bf,
    const int* __restrict__ dec_i, const float* __restrict__ wh_b,
    const float* __restrict__ r_W, const float* __restrict__ r_b,
    const float* __restrict__ swrb, const float* __restrict__ h_state,
    const u16* __restrict__ BtWh, const u16* __restrict__ Sw,
    u16* __restrict__ xin2, float* __restrict__ gates_g,
    u16* __restrict__ Hseq, float* __restrict__ rsum,
    u16* __restrict__ Hw, float* __restrict__ out_att,
    int* __restrict__ sync_cnt)
{
    const int b = blockIdx.x;
    const int tid = threadIdx.x;
    const int w = tid >> 6, l = tid & 63;
    const int lr = l & 15, lk = (l >> 4) << 3;
    __shared__ float h_lds[Hh], c_lds[Hh], fb_lds[Hh], hbuf[Hh];
    __shared__ float red1[256], red2[256];
    __shared__ float rbuf[Pp], attbuf[Pp], rlin_s[Pp], wrV_s[Pp];
    __shared__ float swrb_s;

    // ---- prologue: state + r_lin / wr_sumV ----
    for (int d = tid; d < Hh; d += 256) {
        float v = h_state[b * Hh + d];
        h_lds[d] = v; c_lds[d] = v; fb_lds[d] = 0.f;
    }
    if (tid == 0) swrb_s = swrb[b];
    const int dec_b = dec_i[b];
    for (int pp = w; pp < Pp; pp += 4) {
        const u16* row = props_bf + ((size_t)b * Pp + pp) * Dd;
        float a = 0.f, c = 0.f;
        for (int d = l; d < Dd; d += 64) {
            float x = b2f(row[d]);
            a += x * r_W[d];
            c += x * sum_WRp[d];
        }
        for (int off = 32; off > 0; off >>= 1) {
            a += __shfl_down(a, off);
            c += __shfl_down(c, off);
        }
        if (l == 0) { rlin_s[pp] = a + r_b[0]; wrV_s[pp] = c; }
    }
    __syncthreads();

    int ep = 0;
    for (int t = 0; t < Tm; ++t) {
        // ---- phase 1: this block computes gate cols [b*32, b*32+32) for ALL batches ----
        {
            const int m0 = w * 16;          // batch-row tile per wave
            const int n0 = b * 32;
            const u16* Ap  = xin2 + (size_t)(m0 + lr) * 1024 + lk;
            const u16* Bp0 = Wc + (size_t)(n0 + lr) * 1024 + lk;
            const u16* Bp1 = Wc + (size_t)(n0 + 16 + lr) * 1024 + lk;
            v4f acc0 = {0.f,0.f,0.f,0.f}, acc1 = {0.f,0.f,0.f,0.f};
            for (int k = 0; k < 1024; k += 32) {
                v8bf av = ld8(Ap + k);
                acc0 = __builtin_amdgcn_mfma_f32_16x16x32_bf16(av, ld8(Bp0 + k), acc0, 0, 0, 0);
                acc1 = __builtin_amdgcn_mfma_f32_16x16x32_bf16(av, ld8(Bp1 + k), acc1, 0, 0, 0);
            }
            const int crow0 = (l >> 4) * 4;
            const u16* ge = gates_e + (size_t)t * 64 * Gg;
            #pragma unroll
            for (int r = 0; r < 4; ++r) {
                int bm = m0 + crow0 + r;
                int c0 = n0 + lr, c1 = n0 + 16 + lr;
                gates_g[(size_t)bm * Gg + c0] = acc0[r] + b2f(ge[(size_t)bm * Gg + c0]);
                gates_g[(size_t)bm * Gg + c1] = acc1[r] + b2f(ge[(size_t)bm * Gg + c1]);
            }
        }
        gbar(sync_cnt, 64 * (++ep));

        // ---- phase 2: own-batch LSTM cell + attention ----
        const bool live = t < dec_b;
        float hn_arr[2];
        const float* g = gates_g + (size_t)b * Gg;
        #pragma unroll
        for (int q = 0; q < 2; ++q) {
            int d = tid + q * 256;
            float gi = g[d], gf = g[512 + d], gg = g[1024 + d], go = g[1536 + d];
            float c_old = c_lds[d];
            float si = 1.f / (1.f + expf(-gi));
            float sf = 1.f / (1.f + expf(-gf));
            float so = 1.f / (1.f + expf(-go));
            float cn = sf * c_old + si * tanhf(gg);
            float hn = so * tanhf(cn);
            hbuf[d] = hn;
            hn_arr[q] = hn;
            Hseq[((size_t)(b * Tm + t)) * Hh + d] = f2b(hn);
            float hkeep;
            if (live) { h_lds[d] = hn; c_lds[d] = cn; hkeep = hn; }
            else hkeep = h_lds[d];
            xin2[(size_t)b * 1024 + Hh + d] = f2b(hkeep);
        }
        red1[tid] = hn_arr[0] * sum_WH[tid] + hn_arr[1] * sum_WH[tid + 256];
        red2[tid] = hn_arr[0] * wh_b[tid] + hn_arr[1] * wh_b[tid + 256];
        __syncthreads();
        for (int pp = w; pp < Pp; pp += 4) {
            const float* rh = RH + ((size_t)b * Pp + pp) * Hh;
            float a = 0.f;
            for (int d = l; d < Hh; d += 64) a += rh[d] * hbuf[d];
            for (int off = 32; off > 0; off >>= 1) a += __shfl_down(a, off);
            if (l == 0) rbuf[pp] = a + rlin_s[pp];
        }
        __syncthreads();
        for (int s = 128; s > 0; s >>= 1) {
            if (tid < s) { red1[tid] += red1[tid + s]; red2[tid] += red2[tid + s]; }
            __syncthreads();
        }
        if (tid < 64) {
            float hs = red1[0] + sum_wl[0];
            float logit = -3.4e38f;
            if (tid < Pp) logit = hs + wrV_s[tid] + rbuf[tid];
            float mx = logit;
            for (int off = 32; off > 0; off >>= 1) mx = fmaxf(mx, __shfl_down(mx, off));
            mx = __shfl(mx, 0);
            float ex = (tid < Pp) ? expf(logit - mx) : 0.f;
            float sm = ex;
            for (int off = 32; off > 0; off >>= 1) sm += __shfl_down(sm, off);
            sm = __shfl(sm, 0);
            float att = ex / sm;
            float rs = (tid < Pp) ? rbuf[tid] : 0.f;
            for (int off = 32; off > 0; off >>= 1) rs += __shfl_down(rs, off);
            if (tid == 0) rsum[b * Tm + t] = rs + red2[0] + swrb_s;
            if (tid < Pp) {
                attbuf[tid] = att;
                out_att[((size_t)b * Tm + t) * Pp + tid] = live ? att : 0.f;
            }
        }
        __syncthreads();
        #pragma unroll
        for (int q = 0; q < 2; ++q) {
            int d = tid + q * 256;
            float fbn = 0.f;
            for (int pp = 0; pp < Pp; ++pp)
                fbn += attbuf[pp] * b2f(props_bf[((size_t)b * Pp + pp) * Dd + d]);
            float fbv;
            if (live) { fb_lds[d] = fbn; fbv = fbn; }
            else fbv = fb_lds[d];
            xin2[(size_t)b * 1024 + d] = f2b(fbv);
        }
        gbar(sync_cnt, 64 * (++ep));
    }

    // ---- epilogue: Hw rows for own b: bf16(Hseq[b-rows] @ BtWh + Sw[b]) ----
    {
        const int mbase = b * Tm;
        v4f acc[2][5];
        #pragma unroll
        for (int i = 0; i < 2; ++i)
            #pragma unroll
            for (int j = 0; j < 5; ++j) acc[i][j] = (v4f){0.f,0.f,0.f,0.f};
        const u16* Ap0 = Hseq + (size_t)(mbase + lr) * Hh + lk;
        const u16* Ap1 = Hseq + (size_t)(mbase + 16 + lr) * Hh + lk;
        for (int k = 0; k < Hh; k += 32) {
            v8bf a0 = ld8(Ap0 + k), a1 = ld8(Ap1 + k);
            #pragma unroll
            for (int j = 0; j < 5; ++j) {
                int n = (w * 5 + j) * 16 + lr;
                v8bf bv = ld8(BtWh + (size_t)n * Hh + lk + k);
                acc[0][j] = __builtin_amdgcn_mfma_f32_16x16x32_bf16(a0, bv, acc[0][j], 0, 0, 0);
                acc[1][j] = __builtin_amdgcn_mfma_f32_16x16x32_bf16(a1, bv, acc[1][j], 0, 0, 0);
            }
        }
        const int crow0 = (l >> 4) * 4;
        #pragma unroll
        for (int mt = 0; mt < 2; ++mt) {
            #pragma unroll
            for (int r = 0; r < 4; ++r) {
                int row = mt * 16 + crow0 + r;
                if (row < Tm) {
                    #pragma unroll
                    for (int j = 0; j < 5; ++j) {
                        int n = (w * 5 + j) * 16 + lr;
                        float v = acc[mt][j][r] + b2f(Sw[(size_t)b * Ep + n]);
                        Hw[(size_t)(mbase + row) * Ep + n] = f2b(v);
                    }
                }
            }
        }
    }
}

// ---------------- final predictions GEMM: 128x128, XCD-partitioned ----------------
__global__ __launch_bounds__(256) void gemm_pred_r6(
    const u16* __restrict__ A, const u16* __restrict__ B,
    const float* __restrict__ w_lin, const float* __restrict__ rsum,
    const int* __restrict__ dec, float* __restrict__ outP)
{
    const int id = blockIdx.x;
    const int xcd = id & 7, slot = id >> 3;
    const int q = xcd * 320 + slot;
    const int bm = q % 10;
    const int bn = q / 10;
    if (bn >= 250) return;
    const int tid = threadIdx.x;
    const int w = tid >> 6, l = tid & 63;
    const int wr = w >> 1, wc = w & 1;
    const int lr = l & 15, lk = (l >> 4) << 3;
    const int m0 = bm * 128 + wr * 64;
    const int n0 = bn * 128 + wc * 64;
    const u16* Ap = A + (size_t)(m0 + lr) * Ep + lk;
    const u16* Bp = B + (size_t)(n0 + lr) * Ep + lk;
    v4f acc[4][4];
    #pragma unroll
    for (int i = 0; i < 4; ++i)
        #pragma unroll
        for (int j = 0; j < 4; ++j)
            acc[i][j] = (v4f){0.f,0.f,0.f,0.f};
    for (int k = 0; k < Ep; k += 32) {
        v8bf a[4], bfr[4];
        #pragma unroll
        for (int i = 0; i < 4; ++i) a[i] = ld8(Ap + (size_t)(16 * i) * Ep + k);
        #pragma unroll
        for (int j = 0; j < 4; ++j) bfr[j] = ld8(Bp + (size_t)(16 * j) * Ep + k);
        #pragma unroll
        for (int i = 0; i < 4; ++i)
            #pragma unroll
            for (int j = 0; j < 4; ++j)
                acc[i][j] = __builtin_amdgcn_mfma_f32_16x16x32_bf16(a[i], bfr[j], acc[i][j], 0, 0, 0);
    }
    const int crow0 = (l >> 4) * 4;
    #pragma unroll
    for (int i = 0; i < 4; ++i) {
        #pragma unroll
        for (int r = 0; r < 4; ++r) {
            const int m = m0 + i * 16 + crow0 + r;
            if (m < Mtot) {
                const int b = m / Tm;
                const int t = m - b * Tm;
                const bool live = t < dec[b];
                const float rm = rsum[m];
                #pragma unroll
                for (int j = 0; j < 4; ++j) {
                    const int n = n0 + j * 16 + lr;
                    float v = acc[i][j][r] + w_lin[n] + rm;
                    outP[(size_t)m * Vv + n] = live ? v : 0.f;
                }
            }
        }
    }
}

extern "C" void kernel_launch(void* const* d_in, const int* in_sizes, int n_in,
                              void* d_out, int out_size, void* d_ws, size_t ws_size,
                              hipStream_t stream) {
    float* out = (float*)d_out;
    float* out_pred = out;
    float* out_att  = out + (size_t)Bb * Tm * Vv;
    float* out_caps = out_att + (size_t)Bb * Tm * Pp;
    float* out_dec  = out_caps + Bb * Tm;
    float* out_sort = out_dec + Bb;

    if (n_in != 19) {
        k_sentinel_r6<<<32, 256, 0, stream>>>(out_pred, 10240.f);
        return;
    }
    static const int exp_sizes[19] = {
        Bb * Hh, Bb * Pp * Dd, Bb * Tt, Bb, Vv * Ee,
        Gg * (Ee + Dd), Gg * Hh, Gg, Gg,
        Hh * Ee, Hh, Dd * Ee, Dd, Hh * Dd, Hh, Ee, 1, Dd, 1
    };
    for (int i = 0; i < 19; ++i) {
        if (in_sizes[i] != exp_sizes[i]) {
            k_sentinel_r6<<<32, 256, 0, stream>>>(out_pred, 10752.f + 256.f * i);
            return;
        }
    }
    const int exp_out = Bb * Tm * Vv + Bb * Tm * Pp + Bb * Tm + Bb + Bb;
    if (out_size != exp_out) {
        k_sentinel_r6<<<32, 256, 0, stream>>>(out_pred, 11264.f);
        return;
    }

    char* p = (char*)d_ws;
    auto alloc = [&](size_t bytes) -> char* {
        char* r = p;
        p += (bytes + 255) & ~(size_t)255;
        return r;
    };
    int*   sync_cnt = (int*)alloc(256);
    int*   i_dec    = (int*)alloc(Bb * 4);
    int*   caps_s   = (int*)alloc(Bb * Tt * 4);
    float* h_state  = (float*)alloc(Bb * Hh * 4);
    float* swrb     = (float*)alloc(Bb * 4);
    float* gates_g  = (float*)alloc((size_t)Bb * Gg * 4);
    float* rsum     = (float*)alloc(Mpad * 4);
    float* partialc = (float*)alloc(320 * Ep * 4);
    float* w_lin    = (float*)alloc((size_t)Vv * 4);
    float* sum_WH   = (float*)alloc(Hh * 4);
    float* sum_WRp  = (float*)alloc(Dd * 4);
    float* sum_wl   = (float*)alloc(256);
    float* bias_cat = (float*)alloc(Gg * 4);
    float* RH       = (float*)alloc((size_t)Bb * Pp * Hh * 4);
    u16*   gates_e  = (u16*)alloc((size_t)Tm * Bb * Gg * 2);
    u16*   embp     = (u16*)alloc((size_t)Vv * Ep * 2);
    u16*   BtWh     = (u16*)alloc((size_t)Ep * Hh * 2);
    u16*   BtWr     = (u16*)alloc((size_t)Ep * Hh * 2);
    u16*   rh_bf    = (u16*)alloc((size_t)Hh * Dd * 2);
    u16*   WihE     = (u16*)alloc((size_t)Gg * Ep * 2);
    u16*   Wc       = (u16*)alloc((size_t)Gg * 1024 * 2);
    u16*   props_bf = (u16*)alloc((size_t)Bb * Pp * Dd * 2);
    u16*   S_bf     = (u16*)alloc(Bb * Dd * 2);
    u16*   Sw       = (u16*)alloc(Bb * Ep * 2);
    u16*   xin2     = (u16*)alloc(Bb * 1024 * 2);
    u16*   Hseq     = (u16*)alloc((size_t)Mpad * Hh * 2);
    u16*   Hw       = (u16*)alloc((size_t)Mpad * Ep * 2);
    size_t needed = (size_t)(p - (char*)d_ws);
    if (ws_size < needed) {
        k_sentinel_r6<<<32, 256, 0, stream>>>(out_pred, 10496.f);
        return;
    }

    const float* h0      = (const float*)d_in[0];
    const float* props   = (const float*)d_in[1];
    const int*   captions= (const int*)d_in[2];
    const int*   cap_len = (const int*)d_in[3];
    const float* emb_W   = (const float*)d_in[4];
    const float* W_ih    = (const float*)d_in[5];
    const float* W_hh    = (const float*)d_in[6];
    const float* b_ih    = (const float*)d_in[7];
    const float* b_hh    = (const float*)d_in[8];
    const float* wh_W    = (const float*)d_in[9];
    const float* wh_b    = (const float*)d_in[10];
    const float* wr_W    = (const float*)d_in[11];
    const float* wr_b    = (const float*)d_in[12];
    const float* rh_W    = (const float*)d_in[13];
    const float* rh_b    = (const float*)d_in[14];
    const float* w_W     = (const float*)d_in[15];
    const float* w_b     = (const float*)d_in[16];
    const float* r_W     = (const float*)d_in[17];
    const float* r_b     = (const float*)d_in[18];

    k_pre_r6<<<GPRE, 256, 0, stream>>>(
        h0, props, captions, cap_len, emb_W, W_ih, W_hh, wh_W, wr_W, rh_W,
        b_ih, b_hh, w_W, w_b, wr_b,
        embp, w_lin, partialc, Wc, WihE, BtWh, BtWr, rh_bf, bias_cat,
        h_state, xin2, caps_s, out_caps, props_bf, S_bf, swrb,
        i_dec, out_dec, out_sort, sync_cnt);

    k_gemms_r6<<<906, 256, 0, stream>>>(
        embp, caps_s, WihE, bias_cat, gates_e,
        props_bf, rh_bf, rh_b, RH,
        S_bf, BtWr, Sw,
        partialc, wh_W, wh_b, wr_W, wr_b, w_W, w_b,
        sum_WH, sum_WRp, sum_wl);

    k_loop_r6<<<64, 256, 0, stream>>>(
        Wc, gates_e, sum_WH, sum_wl, sum_WRp, RH, props_bf, i_dec, wh_b,
        r_W, r_b, swrb, h_state, BtWh, Sw,
        xin2, gates_g, Hseq, rsum, Hw, out_att, sync_cnt);

    gemm_pred_r6<<<2560, 256, 0, stream>>>(
        Hw, embp, w_lin, rsum, i_dec, out_pred);
}